// Round 2
// baseline (620.067 us; speedup 1.0000x reference)
//
#include <hip/hip_runtime.h>
#include <hip/hip_bf16.h>
#include <stdint.h>

typedef unsigned short u16;
typedef short bf16x8 __attribute__((ext_vector_type(8)));    // 8 bf16 = 4 VGPRs (MFMA A/B frag)
typedef u16   u16x8  __attribute__((ext_vector_type(8)));
typedef float f32x4  __attribute__((ext_vector_type(4)));    // 16x16 MFMA C/D
typedef float f32x16 __attribute__((ext_vector_type(16)));   // 32x32 MFMA C/D

__device__ __forceinline__ u16 f2bf(float f) {
    uint32_t u = __builtin_bit_cast(uint32_t, f);
    u += 0x7fffu + ((u >> 16) & 1u);   // RNE
    return (u16)(u >> 16);
}

// Problem constants
#define BB 2
#define HH 128
#define WW 256
#define CC 256
#define MM 65536            // BB*HH*WW
#define NQKV 768            // per-axis q|k|v
#define NATT 256            // per-axis attention output

// ---------------------------------------------------------------------------
// prep: pack transposed per-axis weights (bf16), summed bias (fp32)
// ---------------------------------------------------------------------------
__global__ void prep_kernel(
    const float* __restrict__ Wq_h, const float* __restrict__ Wk_h, const float* __restrict__ Wv_h,
    const float* __restrict__ Wo_h, const float* __restrict__ bo_h,
    const float* __restrict__ Wq_w, const float* __restrict__ Wk_w, const float* __restrict__ Wv_w,
    const float* __restrict__ Wo_w, const float* __restrict__ bo_w,
    u16* __restrict__ Wh_t, u16* __restrict__ Ww_t,
    u16* __restrict__ Woh_t, u16* __restrict__ Wow_t, float* __restrict__ bias)
{
    const int tid = blockIdx.x * 256 + threadIdx.x;
    const int nth = gridDim.x * 256;

    // Wh_t / Ww_t : [768][256], n-major (B^T layout). n>>8 selects q/k/v.
    for (int i = tid; i < NQKV * 256; i += nth) {
        int n = i >> 8, kk = i & 255;
        int which = n >> 8, nn = n & 255;
        const float* Wsh = (which == 0) ? Wq_h : (which == 1) ? Wk_h : Wv_h;
        const float* Wsw = (which == 0) ? Wq_w : (which == 1) ? Wk_w : Wv_w;
        Wh_t[i] = f2bf(Wsh[kk * 256 + nn]);
        Ww_t[i] = f2bf(Wsw[kk * 256 + nn]);
    }
    // Woh_t / Wow_t : [256][256], n-major
    for (int i = tid; i < 256 * 256; i += nth) {
        int n = i >> 8, k = i & 255;
        Woh_t[i] = f2bf(Wo_h[k * 256 + n]);
        Wow_t[i] = f2bf(Wo_w[k * 256 + n]);
    }
    for (int i = tid; i < 256; i += nth) bias[i] = bo_h[i] + bo_w[i];
}

// ---------------------------------------------------------------------------
// GEMM: C[M][N] = A[M][K] @ B[K][N], B given as Bt[N][K] (bf16).
// A is bf16 (A16) or fp32 (A32, converted during staging) per AFP32.
// MODE: 0 = bf16 out; 1 = f32 out = acc + bias[col]; 2 = f32 out += acc.
// 128x128 block tile, BK=64, 4 waves each 64x64 via 4x4 of 16x16x32 MFMA.
// XOR swizzle on 16B chunks so ds_read_b128 frag loads are minimal-phase.
// ---------------------------------------------------------------------------
template<int AFP32, int MODE>
__global__ __launch_bounds__(256) void gemm_kernel(
    const u16* __restrict__ A16, const float* __restrict__ A32,
    const u16* __restrict__ Bt, void* __restrict__ Cout,
    const float* __restrict__ bias, int M, int N, int K)
{
    __shared__ u16 As[128 * 64];
    __shared__ u16 Bs[128 * 64];
    const int tid = threadIdx.x;
    const int lane = tid & 63;
    const int wave = tid >> 6;
    const int wm = wave & 1, wn = wave >> 1;
    const int l15 = lane & 15, lq = lane >> 4;
    const int m0 = blockIdx.y * 128, n0 = blockIdx.x * 128;

    f32x4 acc[4][4];
#pragma unroll
    for (int i = 0; i < 4; i++)
#pragma unroll
        for (int j = 0; j < 4; j++)
#pragma unroll
            for (int t = 0; t < 4; t++) acc[i][j][t] = 0.0f;

    for (int kt = 0; kt < K; kt += 64) {
        __syncthreads();
#pragma unroll
        for (int i = 0; i < 4; i++) {
            int cid = i * 256 + tid;        // 1024 chunks of 16B per tile pair
            int r = cid >> 3, sc = cid & 7; // row, LDS slot
            int gk = kt + ((sc ^ (r & 7)) << 3);  // swizzled global k
            if (AFP32) {
                const float* ap = A32 + (size_t)(m0 + r) * K + gk;
                float4 f0 = *(const float4*)ap;
                float4 f1 = *(const float4*)(ap + 4);
                u16 o[8] = { f2bf(f0.x), f2bf(f0.y), f2bf(f0.z), f2bf(f0.w),
                             f2bf(f1.x), f2bf(f1.y), f2bf(f1.z), f2bf(f1.w) };
                *(int4*)(As + (size_t)cid * 8) = *(const int4*)o;
            } else {
                *(int4*)(As + (size_t)cid * 8) = *(const int4*)(A16 + (size_t)(m0 + r) * K + gk);
            }
            *(int4*)(Bs + (size_t)cid * 8) = *(const int4*)(Bt + (size_t)(n0 + r) * K + gk);
        }
        __syncthreads();
#pragma unroll
        for (int ks = 0; ks < 2; ks++) {
            bf16x8 af[4], bfr[4];
#pragma unroll
            for (int i = 0; i < 4; i++) {
                int row = wm * 64 + i * 16 + l15;
                int ca  = ks * 4 + lq;
                af[i]  = *(const bf16x8*)(As + row * 64 + ((ca ^ (row & 7)) << 3));
                int nn  = wn * 64 + i * 16 + l15;
                bfr[i] = *(const bf16x8*)(Bs + nn * 64 + ((ca ^ (nn & 7)) << 3));
            }
#pragma unroll
            for (int i = 0; i < 4; i++)
#pragma unroll
                for (int j = 0; j < 4; j++)
                    acc[i][j] = __builtin_amdgcn_mfma_f32_16x16x32_bf16(af[i], bfr[j], acc[i][j], 0, 0, 0);
        }
    }

    // epilogue: C/D layout col=lane&15, row=(lane>>4)*4+reg
#pragma unroll
    for (int i = 0; i < 4; i++)
#pragma unroll
        for (int j = 0; j < 4; j++)
#pragma unroll
            for (int r = 0; r < 4; r++) {
                int row = m0 + wm * 64 + i * 16 + lq * 4 + r;
                int col = n0 + wn * 64 + j * 16 + l15;
                size_t idx = (size_t)row * N + col;
                if (MODE == 0) {
                    ((u16*)Cout)[idx] = f2bf(acc[i][j][r]);
                } else if (MODE == 1) {
                    ((float*)Cout)[idx] = acc[i][j][r] + bias[col];
                } else {
                    ((float*)Cout)[idx] += acc[i][j][r];
                }
            }
}

// ---------------------------------------------------------------------------
// Attention: one block = (batch, line, head[, q-half]); 4 waves x 32 q-rows.
// S in {128,256}. qkv[M][768] (q:0..255,k:256..511,v:512..767); att[M][256].
// ---------------------------------------------------------------------------
template<int S>
__global__ __launch_bounds__(256) void attn_kernel(
    const u16* __restrict__ qkv, u16* __restrict__ att, int haxis)
{
    constexpr int NC = S / 32;
    __shared__ u16 Vt[32][S + 8];        // stride (S+8)*2 B = 16*odd -> minimal-phase b128 reads
    __shared__ u16 Pbuf[4][32][40];      // per-wave P round-trip (C-layout -> A-layout)

    const int tid = threadIdx.x;
    const int lane = tid & 63;
    const int wave = tid >> 6;
    const int ln = lane & 31;
    const int lh = lane >> 5;

    const int bid = blockIdx.x;
    const int head = bid & 7;
    int mbase, mstride, qs;
    if (haxis) {                          // seq along height: m = (b*128+y)*256 + x
        int xcol = (bid >> 3) & 255;
        int b = bid >> 11;
        mbase = b * 32768 + xcol;
        mstride = 256;
        qs = wave * 32;
    } else {                              // seq along width: m = (b*128+h)*256 + x
        int hrow = (bid >> 3) & 127;
        int b = (bid >> 10) & 1;
        int half = bid >> 11;
        mbase = (b * 128 + hrow) * 256;
        mstride = 1;
        qs = half * 128 + wave * 32;
    }
    const int qcol = head * 32;
    const int kcol = 256 + head * 32;
    const int vcol = 512 + head * 32;

    // ---- stage V transposed: Vt[d][key] ----
    for (int i = tid; i < S * 4; i += 256) {
        int key = i >> 2, dp = i & 3;
        const u16* src = qkv + (size_t)(mbase + key * mstride) * NQKV + vcol + dp * 8;
        u16x8 raw = *(const u16x8*)src;
#pragma unroll
        for (int j = 0; j < 8; j++) Vt[dp * 8 + j][key] = raw[j];
    }
    __syncthreads();

    // ---- Q A-frags (32x32x16: A[m=lane&31][k=(lane>>5)*8+j]) ----
    bf16x8 aq0, aq1;
    {
        const u16* qp = qkv + (size_t)(mbase + (qs + ln) * mstride) * NQKV + qcol + lh * 8;
        aq0 = *(const bf16x8*)qp;
        aq1 = *(const bf16x8*)(qp + 16);
    }

    // ---- scores S = Q K^T ----
    f32x16 sreg[NC];
#pragma unroll
    for (int c = 0; c < NC; c++) {
        const u16* kp = qkv + (size_t)(mbase + (c * 32 + ln) * mstride) * NQKV + kcol + lh * 8;
        bf16x8 bk0 = *(const bf16x8*)kp;
        bf16x8 bk1 = *(const bf16x8*)(kp + 16);
        f32x16 z;
#pragma unroll
        for (int t = 0; t < 16; t++) z[t] = 0.0f;
        z = __builtin_amdgcn_mfma_f32_32x32x16_bf16(aq0, bk0, z, 0, 0, 0);
        z = __builtin_amdgcn_mfma_f32_32x32x16_bf16(aq1, bk1, z, 0, 0, 0);
        sreg[c] = z;
    }

    // ---- softmax (rows in C-layout: row=(r&3)+8*(r>>2)+4*lh; keys across 32 lanes of half-wave) ----
    const float coef = 1.4426950408889634f * 0.17677669529663687f;  // log2(e)/sqrt(32)
    float rinv[16];
    {
        float rmax[16];
#pragma unroll
        for (int r = 0; r < 16; r++) {
            float m = sreg[0][r];
#pragma unroll
            for (int c = 1; c < NC; c++) m = fmaxf(m, sreg[c][r]);
#pragma unroll
            for (int o = 16; o >= 1; o >>= 1) m = fmaxf(m, __shfl_xor(m, o));
            rmax[r] = m;
        }
#pragma unroll
        for (int c = 0; c < NC; c++)
#pragma unroll
            for (int r = 0; r < 16; r++)
                sreg[c][r] = exp2f((sreg[c][r] - rmax[r]) * coef);
#pragma unroll
        for (int r = 0; r < 16; r++) {
            float s = 0.0f;
#pragma unroll
            for (int c = 0; c < NC; c++) s += sreg[c][r];
#pragma unroll
            for (int o = 16; o >= 1; o >>= 1) s += __shfl_xor(s, o);
            rinv[r] = 1.0f / s;
        }
    }

    // ---- O = P V (normalize deferred to epilogue) ----
    f32x16 oacc;
#pragma unroll
    for (int t = 0; t < 16; t++) oacc[t] = 0.0f;

#pragma unroll
    for (int c = 0; c < NC; c++) {
        // write P chunk (C-layout) to per-wave LDS
#pragma unroll
        for (int r = 0; r < 16; r++) {
            int row = (r & 3) + ((r >> 2) << 3) + (lh << 2);
            Pbuf[wave][row][ln] = f2bf(sreg[c][r]);
        }
        // re-read as A-frags: A[m=ln][k=lh*8+j] (+16)
        bf16x8 pa0 = *(const bf16x8*)&Pbuf[wave][ln][lh * 8];
        bf16x8 pa1 = *(const bf16x8*)&Pbuf[wave][ln][16 + lh * 8];
        // V B-frags: B[k=key][n=d] = Vt[d=ln][key]
        bf16x8 bv0 = *(const bf16x8*)&Vt[ln][c * 32 + lh * 8];
        bf16x8 bv1 = *(const bf16x8*)&Vt[ln][c * 32 + 16 + lh * 8];
        oacc = __builtin_amdgcn_mfma_f32_32x32x16_bf16(pa0, bv0, oacc, 0, 0, 0);
        oacc = __builtin_amdgcn_mfma_f32_32x32x16_bf16(pa1, bv1, oacc, 0, 0, 0);
    }

    // ---- epilogue: O C-layout col=ln=d, row matches rinv rows ----
#pragma unroll
    for (int r = 0; r < 16; r++) {
        int row = (r & 3) + ((r >> 2) << 3) + (lh << 2);
        int m = mbase + (qs + row) * mstride;
        att[(size_t)m * NATT + head * 32 + ln] = f2bf(oacc[r] * rinv[r]);
    }
}

// ---------------------------------------------------------------------------
extern "C" void kernel_launch(void* const* d_in, const int* in_sizes, int n_in,
                              void* d_out, int out_size, void* d_ws, size_t ws_size,
                              hipStream_t stream)
{
    (void)in_sizes; (void)n_in; (void)out_size; (void)ws_size;
    const float* x    = (const float*)d_in[0];
    const float* Wq_h = (const float*)d_in[1];
    const float* Wk_h = (const float*)d_in[2];
    const float* Wv_h = (const float*)d_in[3];
    const float* Wo_h = (const float*)d_in[4];
    const float* bo_h = (const float*)d_in[5];
    const float* Wq_w = (const float*)d_in[6];
    const float* Wk_w = (const float*)d_in[7];
    const float* Wv_w = (const float*)d_in[8];
    const float* Wo_w = (const float*)d_in[9];
    const float* bo_w = (const float*)d_in[10];
    // d_in[11]=h, d_in[12]=w : compile-time constants here

    // workspace layout (u16 elems unless noted); total ~129 MiB:
    //   qkvb [65536][768]  : 100.7 MB  (reused across the two axial phases)
    //   attb [65536][256]  :  33.6 MB
    //   Wh_t/Ww_t [768][256], Woh_t/Wow_t [256][256], bias[256] f32 : ~1.05 MB
    u16* qkvb  = (u16*)d_ws;
    u16* attb  = qkvb + (size_t)MM * NQKV;
    u16* Wh_t  = attb + (size_t)MM * NATT;
    u16* Ww_t  = Wh_t + NQKV * 256;
    u16* Woh_t = Ww_t + NQKV * 256;
    u16* Wow_t = Woh_t + 256 * 256;
    float* bias = (float*)(Wow_t + 256 * 256);

    prep_kernel<<<512, 256, 0, stream>>>(Wq_h, Wk_h, Wv_h, Wo_h, bo_h,
                                         Wq_w, Wk_w, Wv_w, Wo_w, bo_w,
                                         Wh_t, Ww_t, Woh_t, Wow_t, bias);

    // ---- phase 1: height-axis ----
    gemm_kernel<1, 0><<<dim3(6, 512), 256, 0, stream>>>(nullptr, x, Wh_t, qkvb, nullptr, MM, NQKV, CC);
    attn_kernel<128><<<4096, 256, 0, stream>>>(qkvb, attb, 1);
    gemm_kernel<0, 1><<<dim3(2, 512), 256, 0, stream>>>(attb, nullptr, Woh_t, d_out, bias, MM, 256, 256);

    // ---- phase 2: width-axis (reuses qkvb/attb) ----
    gemm_kernel<1, 0><<<dim3(6, 512), 256, 0, stream>>>(nullptr, x, Ww_t, qkvb, nullptr, MM, NQKV, CC);
    attn_kernel<256><<<4096, 256, 0, stream>>>(qkvb, attb, 0);
    gemm_kernel<0, 2><<<dim3(2, 512), 256, 0, stream>>>(attb, nullptr, Wow_t, d_out, nullptr, MM, 256, 256);
}

// Round 3
// 540.448 us; speedup vs baseline: 1.1473x; 1.1473x over previous
//
#include <hip/hip_runtime.h>
#include <hip/hip_bf16.h>
#include <stdint.h>

typedef unsigned short u16;
typedef short bf16x8 __attribute__((ext_vector_type(8)));    // 8 bf16 = 4 VGPRs (MFMA A/B frag)
typedef float f32x4  __attribute__((ext_vector_type(4)));    // 16x16 MFMA C/D
typedef float f32x16 __attribute__((ext_vector_type(16)));   // 32x32 MFMA C/D

__device__ __forceinline__ u16 f2bf(float f) {               // RNE
    uint32_t u = __builtin_bit_cast(uint32_t, f);
    u += 0x7fffu + ((u >> 16) & 1u);
    return (u16)(u >> 16);
}
__device__ __forceinline__ u16 f2bf_ru(float f) {            // round-half-up (fast, P only)
    uint32_t u = __builtin_bit_cast(uint32_t, f);
    return (u16)((u + 0x8000u) >> 16);
}

// Problem constants
#define MM 65536            // B*H*W tokens
#define CC 256

// token permutation for h-axis processing: r=(b,x,y) -> memory token m=(b,y,x)
__device__ __forceinline__ int perm_h(int t) {
    return ((t >> 15) << 15) | ((t & 127) << 8) | ((t >> 7) & 255);
}

// ---------------------------------------------------------------------------
// prep: pack transposed per-axis weights (bf16), summed bias (fp32)
// Wh_t/Ww_t[768][256]: rows 0..255 = Wq^T, 256..511 = Wk^T, 512..767 = Wv^T
// ---------------------------------------------------------------------------
__global__ void prep_kernel(
    const float* __restrict__ Wq_h, const float* __restrict__ Wk_h, const float* __restrict__ Wv_h,
    const float* __restrict__ Wo_h, const float* __restrict__ bo_h,
    const float* __restrict__ Wq_w, const float* __restrict__ Wk_w, const float* __restrict__ Wv_w,
    const float* __restrict__ Wo_w, const float* __restrict__ bo_w,
    u16* __restrict__ Wh_t, u16* __restrict__ Ww_t,
    u16* __restrict__ Woh_t, u16* __restrict__ Wow_t, float* __restrict__ bias)
{
    const int tid = blockIdx.x * 256 + threadIdx.x;
    const int nth = gridDim.x * 256;

    for (int i = tid; i < 768 * 256; i += nth) {
        int n = i >> 8, kk = i & 255;
        int which = n >> 8, nn = n & 255;
        const float* Wsh = (which == 0) ? Wq_h : (which == 1) ? Wk_h : Wv_h;
        const float* Wsw = (which == 0) ? Wq_w : (which == 1) ? Wk_w : Wv_w;
        Wh_t[i] = f2bf(Wsh[kk * 256 + nn]);
        Ww_t[i] = f2bf(Wsw[kk * 256 + nn]);
    }
    for (int i = tid; i < 256 * 256; i += nth) {
        int n = i >> 8, k = i & 255;
        Woh_t[i] = f2bf(Wo_h[k * 256 + n]);
        Wow_t[i] = f2bf(Wo_w[k * 256 + n]);
    }
    for (int i = tid; i < 256; i += nth) bias[i] = bo_h[i] + bo_w[i];
}

// ---------------------------------------------------------------------------
// QK projection GEMM: rows = permuted tokens (h: (b,x,y); w: natural),
// cols = 512 (q|k channels). A = x fp32 (converted in staging). Epilogue
// scatters into head-blocked Qb/Kb[g][S][32], g = gi*8+head, gi = row>>log2(S).
// ---------------------------------------------------------------------------
template<int PH>
__global__ __launch_bounds__(256) void gemm_qk_kernel(
    const float* __restrict__ x, const u16* __restrict__ Bt,
    u16* __restrict__ Qb, u16* __restrict__ Kb)
{
    constexpr int S = PH ? 128 : 256;
    constexpr int L = PH ? 7 : 8;
    const int K = 256, N = 512;
    __shared__ u16 As[128 * 64];
    __shared__ u16 Bs[128 * 64];
    const int tid = threadIdx.x;
    const int lane = tid & 63, wave = tid >> 6;
    const int wm = wave & 1, wn = wave >> 1;
    const int l15 = lane & 15, lq = lane >> 4;
    const int m0 = blockIdx.y * 128, n0 = blockIdx.x * 128;

    f32x4 acc[4][4];
#pragma unroll
    for (int i = 0; i < 4; i++)
#pragma unroll
        for (int j = 0; j < 4; j++)
#pragma unroll
            for (int t = 0; t < 4; t++) acc[i][j][t] = 0.0f;

    for (int kt = 0; kt < K; kt += 64) {
        __syncthreads();
#pragma unroll
        for (int i = 0; i < 4; i++) {
            int cid = i * 256 + tid;
            int r = cid >> 3, sc = cid & 7;
            int gk = kt + ((sc ^ (r & 7)) << 3);
            int rm = PH ? perm_h(m0 + r) : (m0 + r);
            const float* ap = x + (size_t)rm * 256 + gk;
            float4 f0 = *(const float4*)ap;
            float4 f1 = *(const float4*)(ap + 4);
            u16 o[8] = { f2bf(f0.x), f2bf(f0.y), f2bf(f0.z), f2bf(f0.w),
                         f2bf(f1.x), f2bf(f1.y), f2bf(f1.z), f2bf(f1.w) };
            *(int4*)(As + (size_t)cid * 8) = *(const int4*)o;
            *(int4*)(Bs + (size_t)cid * 8) = *(const int4*)(Bt + (size_t)(n0 + r) * K + gk);
        }
        __syncthreads();
#pragma unroll
        for (int ks = 0; ks < 2; ks++) {
            bf16x8 af[4], bfr[4];
#pragma unroll
            for (int i = 0; i < 4; i++) {
                int row = wm * 64 + i * 16 + l15;
                int ca  = ks * 4 + lq;
                af[i]  = *(const bf16x8*)(As + row * 64 + ((ca ^ (row & 7)) << 3));
                int nn  = wn * 64 + i * 16 + l15;
                bfr[i] = *(const bf16x8*)(Bs + nn * 64 + ((ca ^ (nn & 7)) << 3));
            }
#pragma unroll
            for (int i = 0; i < 4; i++)
#pragma unroll
                for (int j = 0; j < 4; j++)
                    acc[i][j] = __builtin_amdgcn_mfma_f32_16x16x32_bf16(af[i], bfr[j], acc[i][j], 0, 0, 0);
        }
    }
    (void)N;
    // epilogue: scatter to Qb/Kb[(gi*8+head)*S + seq][d]
#pragma unroll
    for (int i = 0; i < 4; i++)
#pragma unroll
        for (int j = 0; j < 4; j++)
#pragma unroll
            for (int r = 0; r < 4; r++) {
                int rr  = m0 + wm * 64 + i * 16 + lq * 4 + r;
                int col = n0 + wn * 64 + j * 16 + l15;
                int head = (col >> 5) & 7, d = col & 31;
                u16* dst = (col & 256) ? Kb : Qb;
                size_t idx = ((size_t)((rr >> L) * 8 + head) * S + (rr & (S - 1))) * 32 + d;
                dst[idx] = f2bf(acc[i][j][r]);
            }
}

// ---------------------------------------------------------------------------
// V^T projection GEMM: C'[ch][token'] = Wv^T x^T. A = Wv^T bf16 [256][256],
// B rows = permuted tokens of x (fp32->bf16 staging). Epilogue writes
// Vb[g][d][S] with seq contiguous (coalesced).
// ---------------------------------------------------------------------------
template<int PH>
__global__ __launch_bounds__(256) void gemm_vt_kernel(
    const u16* __restrict__ Wt, const float* __restrict__ x, u16* __restrict__ Vb)
{
    constexpr int S = PH ? 128 : 256;
    constexpr int L = PH ? 7 : 8;
    const int K = 256;
    __shared__ u16 As[128 * 64];
    __shared__ u16 Bs[128 * 64];
    const int tid = threadIdx.x;
    const int lane = tid & 63, wave = tid >> 6;
    const int wm = wave & 1, wn = wave >> 1;
    const int l15 = lane & 15, lq = lane >> 4;
    const int m0 = blockIdx.y * 128, n0 = blockIdx.x * 128;

    f32x4 acc[4][4];
#pragma unroll
    for (int i = 0; i < 4; i++)
#pragma unroll
        for (int j = 0; j < 4; j++)
#pragma unroll
            for (int t = 0; t < 4; t++) acc[i][j][t] = 0.0f;

    for (int kt = 0; kt < K; kt += 64) {
        __syncthreads();
#pragma unroll
        for (int i = 0; i < 4; i++) {
            int cid = i * 256 + tid;
            int r = cid >> 3, sc = cid & 7;
            int gk = kt + ((sc ^ (r & 7)) << 3);
            *(int4*)(As + (size_t)cid * 8) = *(const int4*)(Wt + (size_t)(m0 + r) * K + gk);
            int cm = PH ? perm_h(n0 + r) : (n0 + r);
            const float* bp = x + (size_t)cm * 256 + gk;
            float4 f0 = *(const float4*)bp;
            float4 f1 = *(const float4*)(bp + 4);
            u16 o[8] = { f2bf(f0.x), f2bf(f0.y), f2bf(f0.z), f2bf(f0.w),
                         f2bf(f1.x), f2bf(f1.y), f2bf(f1.z), f2bf(f1.w) };
            *(int4*)(Bs + (size_t)cid * 8) = *(const int4*)o;
        }
        __syncthreads();
#pragma unroll
        for (int ks = 0; ks < 2; ks++) {
            bf16x8 af[4], bfr[4];
#pragma unroll
            for (int i = 0; i < 4; i++) {
                int row = wm * 64 + i * 16 + l15;
                int ca  = ks * 4 + lq;
                af[i]  = *(const bf16x8*)(As + row * 64 + ((ca ^ (row & 7)) << 3));
                int nn  = wn * 64 + i * 16 + l15;
                bfr[i] = *(const bf16x8*)(Bs + nn * 64 + ((ca ^ (nn & 7)) << 3));
            }
#pragma unroll
            for (int i = 0; i < 4; i++)
#pragma unroll
                for (int j = 0; j < 4; j++)
                    acc[i][j] = __builtin_amdgcn_mfma_f32_16x16x32_bf16(af[i], bfr[j], acc[i][j], 0, 0, 0);
        }
    }
    // epilogue: Vb[((gi*8+head)*32 + d)*S + seq]
#pragma unroll
    for (int i = 0; i < 4; i++)
#pragma unroll
        for (int j = 0; j < 4; j++)
#pragma unroll
            for (int r = 0; r < 4; r++) {
                int ch = m0 + wm * 64 + i * 16 + lq * 4 + r;   // 0..255
                int n  = n0 + wn * 64 + j * 16 + l15;          // permuted token
                int head = ch >> 5, d = ch & 31;
                int gi = n >> L, seq = n & (S - 1);
                Vb[((size_t)(gi * 8 + head) * 32 + d) * S + seq] = f2bf(acc[i][j][r]);
            }
}

// ---------------------------------------------------------------------------
// Output GEMM: C[M][256] = att[M][K=256] @ Wo. MODE 1: out = acc + bias;
// MODE 2: out += acc.
// ---------------------------------------------------------------------------
template<int MODE>
__global__ __launch_bounds__(256) void gemm_out_kernel(
    const u16* __restrict__ A16, const u16* __restrict__ Bt,
    float* __restrict__ Cout, const float* __restrict__ bias)
{
    const int K = 256, N = 256;
    __shared__ u16 As[128 * 64];
    __shared__ u16 Bs[128 * 64];
    const int tid = threadIdx.x;
    const int lane = tid & 63, wave = tid >> 6;
    const int wm = wave & 1, wn = wave >> 1;
    const int l15 = lane & 15, lq = lane >> 4;
    const int m0 = blockIdx.y * 128, n0 = blockIdx.x * 128;

    f32x4 acc[4][4];
#pragma unroll
    for (int i = 0; i < 4; i++)
#pragma unroll
        for (int j = 0; j < 4; j++)
#pragma unroll
            for (int t = 0; t < 4; t++) acc[i][j][t] = 0.0f;

    for (int kt = 0; kt < K; kt += 64) {
        __syncthreads();
#pragma unroll
        for (int i = 0; i < 4; i++) {
            int cid = i * 256 + tid;
            int r = cid >> 3, sc = cid & 7;
            int gk = kt + ((sc ^ (r & 7)) << 3);
            *(int4*)(As + (size_t)cid * 8) = *(const int4*)(A16 + (size_t)(m0 + r) * K + gk);
            *(int4*)(Bs + (size_t)cid * 8) = *(const int4*)(Bt + (size_t)(n0 + r) * K + gk);
        }
        __syncthreads();
#pragma unroll
        for (int ks = 0; ks < 2; ks++) {
            bf16x8 af[4], bfr[4];
#pragma unroll
            for (int i = 0; i < 4; i++) {
                int row = wm * 64 + i * 16 + l15;
                int ca  = ks * 4 + lq;
                af[i]  = *(const bf16x8*)(As + row * 64 + ((ca ^ (row & 7)) << 3));
                int nn  = wn * 64 + i * 16 + l15;
                bfr[i] = *(const bf16x8*)(Bs + nn * 64 + ((ca ^ (nn & 7)) << 3));
            }
#pragma unroll
            for (int i = 0; i < 4; i++)
#pragma unroll
                for (int j = 0; j < 4; j++)
                    acc[i][j] = __builtin_amdgcn_mfma_f32_16x16x32_bf16(af[i], bfr[j], acc[i][j], 0, 0, 0);
        }
    }
#pragma unroll
    for (int i = 0; i < 4; i++)
#pragma unroll
        for (int j = 0; j < 4; j++)
#pragma unroll
            for (int r = 0; r < 4; r++) {
                int row = m0 + wm * 64 + i * 16 + lq * 4 + r;
                int col = n0 + wn * 64 + j * 16 + l15;
                size_t idx = (size_t)row * N + col;
                if (MODE == 1) Cout[idx] = acc[i][j][r] + bias[col];
                else           Cout[idx] += acc[i][j][r];
            }
}

// ---------------------------------------------------------------------------
// Attention, barrier-free: block = (gi, head[, q-half]); 4 waves x 32 q-rows.
// Qb/Kb[g][S][32], Vb[g][32][S]. Two-pass softmax (QK^T recomputed in pass 2).
// att[m][256] output (token-major, feeds gemm_out).
// ---------------------------------------------------------------------------
template<int S, int PH>
__global__ __launch_bounds__(256) void attn_kernel(
    const u16* __restrict__ Qb, const u16* __restrict__ Kb,
    const u16* __restrict__ Vb, u16* __restrict__ att)
{
    constexpr int NC = S / 32;
    __shared__ u16 Pbuf[4][32][40];

    const int tid = threadIdx.x;
    const int lane = tid & 63;
    const int wave = tid >> 6;
    const int ln = lane & 31;
    const int lh = lane >> 5;

    const int bid = blockIdx.x;
    const int head = bid & 7;
    const int rest = bid >> 3;            // [0,512)
    int gi, qs;
    if (PH) { gi = rest;        qs = wave * 32; }
    else    { gi = rest & 255;  qs = ((rest >> 8) << 7) + wave * 32; }
    const int g = gi * 8 + head;

    const u16* Qg = Qb + (size_t)g * S * 32;
    const u16* Kg = Kb + (size_t)g * S * 32;
    const u16* Vg = Vb + (size_t)g * 32 * S;

    // Q A-frags (32x32x16: A[m=ln][k=lh*8+j], +16)
    const u16* qp = Qg + (qs + ln) * 32 + lh * 8;
    bf16x8 aq0 = *(const bf16x8*)qp;
    bf16x8 aq1 = *(const bf16x8*)(qp + 16);

    const float coef = 1.4426950408889634f * 0.17677669529663687f;  // log2(e)/sqrt(32)

    // ---- pass 1: row max ----
    float rmax[16];
#pragma unroll
    for (int r = 0; r < 16; r++) rmax[r] = -3.0e38f;
#pragma unroll
    for (int c = 0; c < NC; c++) {
        const u16* kp = Kg + (c * 32 + ln) * 32 + lh * 8;
        bf16x8 bk0 = *(const bf16x8*)kp;
        bf16x8 bk1 = *(const bf16x8*)(kp + 16);
        f32x16 z;
#pragma unroll
        for (int t = 0; t < 16; t++) z[t] = 0.0f;
        z = __builtin_amdgcn_mfma_f32_32x32x16_bf16(aq0, bk0, z, 0, 0, 0);
        z = __builtin_amdgcn_mfma_f32_32x32x16_bf16(aq1, bk1, z, 0, 0, 0);
#pragma unroll
        for (int r = 0; r < 16; r++) rmax[r] = fmaxf(rmax[r], z[r]);
    }
    float mc[16];
#pragma unroll
    for (int r = 0; r < 16; r++) {
        float m = rmax[r];
#pragma unroll
        for (int o = 16; o >= 1; o >>= 1) m = fmaxf(m, __shfl_xor(m, o));
        mc[r] = m * coef;
    }

    // ---- pass 2: exp, sum, PV ----
    float rsum[16];
#pragma unroll
    for (int r = 0; r < 16; r++) rsum[r] = 0.0f;
    f32x16 oacc;
#pragma unroll
    for (int t = 0; t < 16; t++) oacc[t] = 0.0f;

#pragma unroll
    for (int c = 0; c < NC; c++) {
        const u16* kp = Kg + (c * 32 + ln) * 32 + lh * 8;
        bf16x8 bk0 = *(const bf16x8*)kp;
        bf16x8 bk1 = *(const bf16x8*)(kp + 16);
        f32x16 z;
#pragma unroll
        for (int t = 0; t < 16; t++) z[t] = 0.0f;
        z = __builtin_amdgcn_mfma_f32_32x32x16_bf16(aq0, bk0, z, 0, 0, 0);
        z = __builtin_amdgcn_mfma_f32_32x32x16_bf16(aq1, bk1, z, 0, 0, 0);
#pragma unroll
        for (int r = 0; r < 16; r++) {
            float p = exp2f(z[r] * coef - mc[r]);
            rsum[r] += p;
            int row = (r & 3) + ((r >> 2) << 3) + (lh << 2);
            Pbuf[wave][row][ln] = f2bf_ru(p);
        }
        bf16x8 pa0 = *(const bf16x8*)&Pbuf[wave][ln][lh * 8];
        bf16x8 pa1 = *(const bf16x8*)&Pbuf[wave][ln][16 + lh * 8];
        const u16* vp = Vg + ln * S + c * 32 + lh * 8;
        bf16x8 bv0 = *(const bf16x8*)vp;
        bf16x8 bv1 = *(const bf16x8*)(vp + 16);
        oacc = __builtin_amdgcn_mfma_f32_32x32x16_bf16(pa0, bv0, oacc, 0, 0, 0);
        oacc = __builtin_amdgcn_mfma_f32_32x32x16_bf16(pa1, bv1, oacc, 0, 0, 0);
    }

    // ---- epilogue ----
#pragma unroll
    for (int r = 0; r < 16; r++) {
        float s = rsum[r];
#pragma unroll
        for (int o = 16; o >= 1; o >>= 1) s += __shfl_xor(s, o);
        int row = (r & 3) + ((r >> 2) << 3) + (lh << 2);
        int seq = qs + row;
        int m = PH ? ((gi >> 8) * 32768 + seq * 256 + (gi & 255))
                   : (gi * 256 + seq);
        att[(size_t)m * 256 + head * 32 + ln] = f2bf(oacc[r] * (1.0f / s));
    }
}

// ---------------------------------------------------------------------------
extern "C" void kernel_launch(void* const* d_in, const int* in_sizes, int n_in,
                              void* d_out, int out_size, void* d_ws, size_t ws_size,
                              hipStream_t stream)
{
    (void)in_sizes; (void)n_in; (void)out_size; (void)ws_size;
    const float* x    = (const float*)d_in[0];
    const float* Wq_h = (const float*)d_in[1];
    const float* Wk_h = (const float*)d_in[2];
    const float* Wv_h = (const float*)d_in[3];
    const float* Wo_h = (const float*)d_in[4];
    const float* bo_h = (const float*)d_in[5];
    const float* Wq_w = (const float*)d_in[6];
    const float* Wk_w = (const float*)d_in[7];
    const float* Wv_w = (const float*)d_in[8];
    const float* Wo_w = (const float*)d_in[9];
    const float* bo_w = (const float*)d_in[10];

    // workspace (u16 elems unless noted), total ~135 MB:
    //   Qb,Kb,Vb [M*256] each : 33.55 MB x3  (reused across phases)
    //   attb     [M][256]     : 33.55 MB
    //   Wh_t/Ww_t [768][256], Woh_t/Wow_t [256][256], bias[256] f32
    u16* Qb   = (u16*)d_ws;
    u16* Kb   = Qb + (size_t)MM * 256;
    u16* Vb   = Kb + (size_t)MM * 256;
    u16* attb = Vb + (size_t)MM * 256;
    u16* Wh_t = attb + (size_t)MM * 256;
    u16* Ww_t = Wh_t + 768 * 256;
    u16* Woh_t = Ww_t + 768 * 256;
    u16* Wow_t = Woh_t + 256 * 256;
    float* bias = (float*)(Wow_t + 256 * 256);

    prep_kernel<<<512, 256, 0, stream>>>(Wq_h, Wk_h, Wv_h, Wo_h, bo_h,
                                         Wq_w, Wk_w, Wv_w, Wo_w, bo_w,
                                         Wh_t, Ww_t, Woh_t, Wow_t, bias);

    // ---- phase 1: height-axis (S=128, permuted token order (b,x,y)) ----
    gemm_qk_kernel<1><<<dim3(4, 512), 256, 0, stream>>>(x, Wh_t, Qb, Kb);
    gemm_vt_kernel<1><<<dim3(512, 2), 256, 0, stream>>>(Wh_t + 512 * 256, x, Vb);
    attn_kernel<128, 1><<<4096, 256, 0, stream>>>(Qb, Kb, Vb, attb);
    gemm_out_kernel<1><<<dim3(2, 512), 256, 0, stream>>>(attb, Woh_t, (float*)d_out, bias);

    // ---- phase 2: width-axis (S=256, natural token order) ----
    gemm_qk_kernel<0><<<dim3(4, 512), 256, 0, stream>>>(x, Ww_t, Qb, Kb);
    gemm_vt_kernel<0><<<dim3(512, 2), 256, 0, stream>>>(Ww_t + 512 * 256, x, Vb);
    attn_kernel<256, 0><<<4096, 256, 0, stream>>>(Qb, Kb, Vb, attb);
    gemm_out_kernel<2><<<dim3(2, 512), 256, 0, stream>>>(attb, Wow_t, (float*)d_out, nullptr);
}